// Round 4
// baseline (1093.682 us; speedup 1.0000x reference)
//
#include <hip/hip_runtime.h>
#include <hip/hip_fp16.h>

#define B_ 4
#define S_ 4096
#define H_ 16
#define D_ 1024
#define HD_ 64

// (tanh(x)+1)/2 == sigmoid(2x)
__device__ __forceinline__ float featmap(float x) {
  float e = __expf(-2.0f * x);
  return __builtin_amdgcn_rcpf(1.0f + e);
}

union F2H2 { float f; __half2 h; };
__device__ __forceinline__ __half2 asH2(float f) { F2H2 u; u.f = f; return u.h; }

// ---------------- Phase 1: partial KV (64x64) + partial ksum per (b,h,chunk)
// k,v staged as f16 tiles (halves LDS read traffic -> LDS no longer 1.9x FMA).
__global__ __launch_bounds__(256, 4) void mh_p1(
    const float* __restrict__ kg, const float* __restrict__ vg,
    float* __restrict__ kvp, float* __restrict__ kredp, int nc) {
  __shared__ char pool[32768];
  __half (*kt)[64] = (__half(*)[64])pool;           // 8KB
  __half (*vt)[64] = (__half(*)[64])(pool + 8192);  // 8KB
  float* sA = (float*)pool;                          // 16KB overlay (after compute)
  float* sB = (float*)(pool + 16384);                // 16KB
  __shared__ float ksr[4][64];

  const int bid = blockIdx.x;
  const int bh  = bid & 63;
  const int c   = bid >> 6;
  const int b   = bh >> 4, h = bh & 15;
  const int t    = threadIdx.x;
  const int w    = t >> 6;
  const int lane = t & 63;
  const int dg = lane >> 3, eg = lane & 7;
  const int d0 = dg * 8, e0 = eg * 8;

  const size_t rowbase = (size_t)b * S_ * D_ + (size_t)h * HD_;
  const float* kb = kg + rowbase;
  const float* vb = vg + rowbase;
  const int ch = S_ / nc;
  const int s0 = c * ch;
  const int ntiles = ch / 64;

  float acc[8][8];
#pragma unroll
  for (int i = 0; i < 8; ++i)
#pragma unroll
    for (int j = 0; j < 8; ++j) acc[i][j] = 0.f;
  float ks = 0.f;

#pragma unroll 1
  for (int tile = 0; tile < ntiles; ++tile) {
    const int rb = s0 + tile * 64 + w * 16;
    // wave w owns rows [w*16, w*16+16): no cross-wave hazard, no barrier
#pragma unroll
    for (int i = 0; i < 16; ++i) {
      const size_t g = (size_t)(rb + i) * D_ + lane;
      float kh = featmap(kb[g]);
      kt[w * 16 + i][lane] = __float2half(kh);
      vt[w * 16 + i][lane] = __float2half(vb[g]);
      ks += kh;
    }
#pragma unroll
    for (int i = 0; i < 16; ++i) {
      const int r = w * 16 + i;
      float4 kraw = *(const float4*)&kt[r][d0];   // 8 halves
      float4 vraw = *(const float4*)&vt[r][e0];
      __half2 kh2[4] = {asH2(kraw.x), asH2(kraw.y), asH2(kraw.z), asH2(kraw.w)};
      __half2 vh2[4] = {asH2(vraw.x), asH2(vraw.y), asH2(vraw.z), asH2(vraw.w)};
      float kd[8], ve[8];
#pragma unroll
      for (int p = 0; p < 4; ++p) {
        kd[2 * p] = __low2float(kh2[p]);  kd[2 * p + 1] = __high2float(kh2[p]);
        ve[2 * p] = __low2float(vh2[p]);  ve[2 * p + 1] = __high2float(vh2[p]);
      }
#pragma unroll
      for (int di = 0; di < 8; ++di)
#pragma unroll
        for (int ej = 0; ej < 8; ++ej) acc[di][ej] += kd[di] * ve[ej];
    }
  }

  // ---- reduce 4 wave replicas through LDS (overlay scratch), no atomics
  ksr[w][lane] = ks;
  __syncthreads();   // all waves done with kt/vt -> safe to overlay
  if (w >= 2) {
    float* dst = (w == 2) ? sA : sB;
#pragma unroll
    for (int di = 0; di < 8; ++di) {
      float4 a = {acc[di][0], acc[di][1], acc[di][2], acc[di][3]};
      float4 bq = {acc[di][4], acc[di][5], acc[di][6], acc[di][7]};
      *(float4*)&dst[(d0 + di) * 64 + e0] = a;
      *(float4*)&dst[(d0 + di) * 64 + e0 + 4] = bq;
    }
  }
  __syncthreads();
  if (w < 2) {
    const float* src = (w == 0) ? sA : sB;
#pragma unroll
    for (int di = 0; di < 8; ++di)
#pragma unroll
      for (int ej = 0; ej < 8; ++ej) acc[di][ej] += src[(d0 + di) * 64 + e0 + ej];
  }
  __syncthreads();
  if (w == 1) {
#pragma unroll
    for (int di = 0; di < 8; ++di) {
      float4 a = {acc[di][0], acc[di][1], acc[di][2], acc[di][3]};
      float4 bq = {acc[di][4], acc[di][5], acc[di][6], acc[di][7]};
      *(float4*)&sA[(d0 + di) * 64 + e0] = a;
      *(float4*)&sA[(d0 + di) * 64 + e0 + 4] = bq;
    }
  }
  __syncthreads();
  if (w == 0) {
    float* dst = kvp + ((size_t)(c * 64 + bh)) * 4096;
#pragma unroll
    for (int di = 0; di < 8; ++di) {
#pragma unroll
      for (int ej = 0; ej < 8; ++ej) acc[di][ej] += sA[(d0 + di) * 64 + e0 + ej];
      float4 a = {acc[di][0], acc[di][1], acc[di][2], acc[di][3]};
      float4 bq = {acc[di][4], acc[di][5], acc[di][6], acc[di][7]};
      *(float4*)&dst[(d0 + di) * 64 + e0] = a;
      *(float4*)&dst[(d0 + di) * 64 + e0 + 4] = bq;
    }
  }
  if (t < 64) {
    float tot = ksr[0][t] + ksr[1][t] + ksr[2][t] + ksr[3][t];
    kredp[(size_t)(c * 64 + bh) * 64 + t] = tot;
  }
}

// ---------------- Phase 1.5: reduce chunk partials -> kv, kred
__global__ __launch_bounds__(256) void mh_p15(
    const float* __restrict__ kvp, const float* __restrict__ kredp,
    float* __restrict__ kv, float* __restrict__ kred, int nc) {
  const int i = blockIdx.x * 256 + threadIdx.x;
  float s = 0.f;
#pragma unroll 1
  for (int c = 0; c < nc; ++c) s += kvp[(size_t)c * (64 * 4096) + i];
  kv[i] = s;
  if (i < 64 * 64) {
    float r = 0.f;
#pragma unroll 1
    for (int c = 0; c < nc; ++c) r += kredp[c * 4096 + i];
    kred[i] = r + 1e-8f;
  }
}

// ---------------- Phase 2: out = z * qh @ KV  (register-tiled via LDS)
// Block: one (b,h) x 256 s-rows, 4 waves. Each wave owns 64 rows x 64 cols;
// lane owns 8 rows (stride 8: rows = rg + 8*rr) x 8 cols (cg*8..+8).
// q tile f16 [256][68] (pad 68 -> row-read insts hit 16 distinct banks),
// kv tile f16 [64][64], kred f32. Every LDS value amortized over 8 FMAs.
__global__ __launch_bounds__(256, 3) void mh_p2(
    const float* __restrict__ qg, const float* __restrict__ kvg,
    const float* __restrict__ kredg, float* __restrict__ outg) {
  __shared__ __half qt[256][68];   // 34816 B
  __shared__ __half kvt[64][64];   // 8192 B
  __shared__ float kreds[64];

  const int bid = blockIdx.x;          // 0..1023
  const int bh = bid >> 4;             // 0..63
  const int chunk = bid & 15;
  const int b = bh >> 4, h = bh & 15;
  const int blockrow = chunk * 256;
  const int t = threadIdx.x;
  const int w = t >> 6, lane = t & 63;
  const int rg = lane >> 3, cg = lane & 7;
  const int lrow0 = w * 64 + rg;       // lane's rows: lrow0 + 8*rr

  // ---- stage q tile (featmap -> f16), coalesced
  const int tr = t >> 4, tc4 = (t & 15) * 4;
#pragma unroll
  for (int i = 0; i < 16; ++i) {
    const int row = tr + i * 16;
    float4 qv = *(const float4*)&qg[((size_t)(b * S_) + blockrow + row) * D_ + h * HD_ + tc4];
    qt[row][tc4 + 0] = __float2half(featmap(qv.x));
    qt[row][tc4 + 1] = __float2half(featmap(qv.y));
    qt[row][tc4 + 2] = __float2half(featmap(qv.z));
    qt[row][tc4 + 3] = __float2half(featmap(qv.w));
  }
  // ---- stage kv tile (f32 -> f16) + kred
  {
    __half* kvflat = &kvt[0][0];
#pragma unroll
    for (int i = 0; i < 8; ++i) {
      const int idx = i * 512 + t * 2;
      float2 kvv = *(const float2*)&kvg[(size_t)bh * 4096 + idx];
      kvflat[idx]     = __float2half(kvv.x);
      kvflat[idx + 1] = __float2half(kvv.y);
    }
    if (t < 16) {
      float4 kr = *(const float4*)&kredg[bh * 64 + t * 4];
      kreds[t * 4 + 0] = kr.x; kreds[t * 4 + 1] = kr.y;
      kreds[t * 4 + 2] = kr.z; kreds[t * 4 + 3] = kr.w;
    }
  }
  __syncthreads();

  float acc[8][8];
#pragma unroll
  for (int i = 0; i < 8; ++i)
#pragma unroll
    for (int j = 0; j < 8; ++j) acc[i][j] = 0.f;
  float zacc[8];
#pragma unroll
  for (int i = 0; i < 8; ++i) zacc[i] = 0.f;

#pragma unroll 1
  for (int kc = 0; kc < 16; ++kc) {
    // q packs: 8 rows (stride 8), 4 halves each (b64, conflict-free)
    __half2 qp[8][2];
#pragma unroll
    for (int rr = 0; rr < 8; ++rr) {
      float2 qraw = *(const float2*)&qt[lrow0 + 8 * rr][kc * 4];
      qp[rr][0] = asH2(qraw.x);
      qp[rr][1] = asH2(qraw.y);
    }
    float4 kr4 = *(const float4*)&kreds[kc * 4];
    const float krj[4] = {kr4.x, kr4.y, kr4.z, kr4.w};
#pragma unroll
    for (int j = 0; j < 4; ++j) {
      const int k = kc * 4 + j;
      float4 kvraw = *(const float4*)&kvt[k][cg * 8];   // 8 halves (b128)
      __half2 kvh[4] = {asH2(kvraw.x), asH2(kvraw.y), asH2(kvraw.z), asH2(kvraw.w)};
      float kvf[8];
#pragma unroll
      for (int p = 0; p < 4; ++p) {
        kvf[2 * p] = __low2float(kvh[p]);
        kvf[2 * p + 1] = __high2float(kvh[p]);
      }
#pragma unroll
      for (int rr = 0; rr < 8; ++rr) {
        const float qf = (j == 0) ? __low2float(qp[rr][0])
                       : (j == 1) ? __high2float(qp[rr][0])
                       : (j == 2) ? __low2float(qp[rr][1])
                                  : __high2float(qp[rr][1]);
        zacc[rr] += qf * krj[j];
#pragma unroll
        for (int e = 0; e < 8; ++e) acc[rr][e] += qf * kvf[e];
      }
    }
  }

  // ---- epilogue: scale by z, write out (rows consecutive across rg lanes)
#pragma unroll
  for (int rr = 0; rr < 8; ++rr) {
    const float z = __builtin_amdgcn_rcpf(zacc[rr]);
    const int grow = blockrow + w * 64 + rg + 8 * rr;
    float* op = &outg[((size_t)(b * S_) + grow) * D_ + h * HD_ + cg * 8];
    float4 o0 = {acc[rr][0] * z, acc[rr][1] * z, acc[rr][2] * z, acc[rr][3] * z};
    float4 o1 = {acc[rr][4] * z, acc[rr][5] * z, acc[rr][6] * z, acc[rr][7] * z};
    *(float4*)op = o0;
    *(float4*)(op + 4) = o1;
  }
}

extern "C" void kernel_launch(void* const* d_in, const int* in_sizes, int n_in,
                              void* d_out, int out_size, void* d_ws, size_t ws_size,
                              hipStream_t stream) {
  const float* q = (const float*)d_in[0];
  const float* k = (const float*)d_in[1];
  const float* v = (const float*)d_in[2];
  float* out = (float*)d_out;
  float* ws = (float*)d_ws;

  const int nc = (ws_size >= (size_t)18 * 1024 * 1024) ? 16 : 8;

  float* kv    = ws;                          // 1 MiB
  float* kred  = ws + 262144;                 // 16 KiB
  float* kvp   = ws + 262144 + 4096;          // nc MiB
  float* kredp = kvp + (size_t)nc * 262144;

  mh_p1 <<<64 * nc, 256, 0, stream>>>(k, v, kvp, kredp, nc);
  mh_p15<<<1024,    256, 0, stream>>>(kvp, kredp, kv, kred, nc);
  mh_p2 <<<64 * 16, 256, 0, stream>>>(q, kv, kred, out);
}

// Round 5
// 93.993 us; speedup vs baseline: 11.6358x; 11.6358x over previous
//
#include <hip/hip_runtime.h>
#include <hip/hip_fp16.h>

#define B_ 4
#define S_ 4096
#define H_ 16
#define D_ 1024
#define HD_ 64

// (tanh(x)+1)/2 == sigmoid(2x)
__device__ __forceinline__ float featmap(float x) {
  float e = __expf(-2.0f * x);
  return __builtin_amdgcn_rcpf(1.0f + e);
}

union F2H2 { float f; __half2 h; };
__device__ __forceinline__ __half2 asH2(float f) { F2H2 u; u.f = f; return u.h; }

// ---------------- Phase 1: partial KV (64x64) + partial ksum per (b,h,chunk)
// R1's proven f32-staged structure; NC compile-time (runtime nc cost +10us in
// R2/R3; f16 repack in R4 spilled acc to scratch: VGPR=64, 3.5GB HBM traffic).
template <int NC>
__global__ __launch_bounds__(256, 2) void mh_p1(
    const float* __restrict__ kg, const float* __restrict__ vg,
    float* __restrict__ kvp, float* __restrict__ kredp) {
  __shared__ float kt[64][64];
  __shared__ float vt[64][64];
  __shared__ float ksr[4][64];

  const int bid = blockIdx.x;       // 0..64*NC-1
  const int bh  = bid & 63;         // b*16+h
  const int c   = bid >> 6;         // chunk
  const int b   = bh >> 4, h = bh & 15;
  const int t    = threadIdx.x;
  const int w    = t >> 6;          // wave 0..3
  const int lane = t & 63;
  const int dg = lane >> 3, eg = lane & 7;
  const int d0 = dg * 8, e0 = eg * 8;

  const size_t rowbase = (size_t)b * S_ * D_ + (size_t)h * HD_;
  const float* kb = kg + rowbase;
  const float* vb = vg + rowbase;
  constexpr int CH = S_ / NC;
  const int s0 = c * CH;

  float acc[8][8];
#pragma unroll
  for (int i = 0; i < 8; ++i)
#pragma unroll
    for (int j = 0; j < 8; ++j) acc[i][j] = 0.f;
  float ks = 0.f;  // partial column-sum of sigmoid(k), column = lane

#pragma unroll 1
  for (int tile = 0; tile < CH / 64; ++tile) {
    const int rb = s0 + tile * 64 + w * 16;
    // wave w owns rows [w*16, w*16+16) -> no cross-wave hazard, no barrier
#pragma unroll
    for (int i = 0; i < 16; ++i) {
      const size_t g = (size_t)(rb + i) * D_ + lane;
      float kh = featmap(kb[g]);
      float vv = vb[g];
      kt[w * 16 + i][lane] = kh;
      vt[w * 16 + i][lane] = vv;
      ks += kh;
    }
#pragma unroll
    for (int i = 0; i < 16; ++i) {
      const int r = w * 16 + i;
      float4 k0 = *(const float4*)&kt[r][d0];
      float4 k1 = *(const float4*)&kt[r][d0 + 4];
      float4 v0 = *(const float4*)&vt[r][e0];
      float4 v1 = *(const float4*)&vt[r][e0 + 4];
      float kd[8] = {k0.x, k0.y, k0.z, k0.w, k1.x, k1.y, k1.z, k1.w};
      float ve[8] = {v0.x, v0.y, v0.z, v0.w, v1.x, v1.y, v1.z, v1.w};
#pragma unroll
      for (int di = 0; di < 8; ++di)
#pragma unroll
        for (int ej = 0; ej < 8; ++ej) acc[di][ej] += kd[di] * ve[ej];
    }
  }

  // ---- reduce 4 wave replicas (tree through LDS), no atomics
  ksr[w][lane] = ks;
  __syncthreads();
  float* ktf = &kt[0][0];
  float* vtf = &vt[0][0];
  if (w >= 2) {
    float* dst = (w == 2) ? ktf : vtf;
#pragma unroll
    for (int di = 0; di < 8; ++di) {
      float4 a = {acc[di][0], acc[di][1], acc[di][2], acc[di][3]};
      float4 bq = {acc[di][4], acc[di][5], acc[di][6], acc[di][7]};
      *(float4*)&dst[(d0 + di) * 64 + e0] = a;
      *(float4*)&dst[(d0 + di) * 64 + e0 + 4] = bq;
    }
  }
  __syncthreads();
  if (w < 2) {
    const float* src = (w == 0) ? ktf : vtf;
#pragma unroll
    for (int di = 0; di < 8; ++di)
#pragma unroll
      for (int ej = 0; ej < 8; ++ej) acc[di][ej] += src[(d0 + di) * 64 + e0 + ej];
  }
  __syncthreads();
  if (w == 1) {
#pragma unroll
    for (int di = 0; di < 8; ++di) {
      float4 a = {acc[di][0], acc[di][1], acc[di][2], acc[di][3]};
      float4 bq = {acc[di][4], acc[di][5], acc[di][6], acc[di][7]};
      *(float4*)&ktf[(d0 + di) * 64 + e0] = a;
      *(float4*)&ktf[(d0 + di) * 64 + e0 + 4] = bq;
    }
  }
  __syncthreads();
  if (w == 0) {
    float* dst = kvp + ((size_t)(c * 64 + bh)) * 4096;
#pragma unroll
    for (int di = 0; di < 8; ++di) {
#pragma unroll
      for (int ej = 0; ej < 8; ++ej) acc[di][ej] += ktf[(d0 + di) * 64 + e0 + ej];
      float4 a = {acc[di][0], acc[di][1], acc[di][2], acc[di][3]};
      float4 bq = {acc[di][4], acc[di][5], acc[di][6], acc[di][7]};
      *(float4*)&dst[(d0 + di) * 64 + e0] = a;
      *(float4*)&dst[(d0 + di) * 64 + e0 + 4] = bq;
    }
  }
  if (t < 64) {
    float tot = ksr[0][t] + ksr[1][t] + ksr[2][t] + ksr[3][t];
    kredp[(size_t)(c * 64 + bh) * 64 + t] = tot;
  }
}

// ---------------- Phase 1.5: reduce chunk partials -> kv, kred
template <int NC>
__global__ __launch_bounds__(256) void mh_p15(
    const float* __restrict__ kvp, const float* __restrict__ kredp,
    float* __restrict__ kv, float* __restrict__ kred) {
  const int i = blockIdx.x * 256 + threadIdx.x;  // 0..262143
  float s = 0.f;
#pragma unroll
  for (int c = 0; c < NC; ++c) s += kvp[(size_t)c * (64 * 4096) + i];
  kv[i] = s;
  if (i < 64 * 64) {
    float r = 0.f;
#pragma unroll
    for (int c = 0; c < NC; ++c) r += kredp[c * 4096 + i];
    kred[i] = r + 1e-8f;
  }
}

// ---------------- Phase 2: out = z * qh @ KV  (register-tiled via LDS)
// Block: one (b,h) x 256 s-rows, 4 waves. Each wave owns 64 rows x 64 cols;
// lane owns 8 rows (stride 8: rows = rg + 8*rr) x 8 cols (cg*8..+8).
// q tile f16 [256][68] (pad 68 -> row-reads hit 16 distinct banks),
// kv tile f16 [64][64], kred f32. Every LDS value amortized over 8 FMAs.
// (Proven ~30us in R4.)
__global__ __launch_bounds__(256, 3) void mh_p2(
    const float* __restrict__ qg, const float* __restrict__ kvg,
    const float* __restrict__ kredg, float* __restrict__ outg) {
  __shared__ __half qt[256][68];   // 34816 B
  __shared__ __half kvt[64][64];   // 8192 B
  __shared__ float kreds[64];

  const int bid = blockIdx.x;          // 0..1023
  const int bh = bid >> 4;             // 0..63
  const int chunk = bid & 15;
  const int b = bh >> 4, h = bh & 15;
  const int blockrow = chunk * 256;
  const int t = threadIdx.x;
  const int w = t >> 6, lane = t & 63;
  const int rg = lane >> 3, cg = lane & 7;
  const int lrow0 = w * 64 + rg;       // lane's rows: lrow0 + 8*rr

  // ---- stage q tile (featmap -> f16), coalesced
  const int tr = t >> 4, tc4 = (t & 15) * 4;
#pragma unroll
  for (int i = 0; i < 16; ++i) {
    const int row = tr + i * 16;
    float4 qv = *(const float4*)&qg[((size_t)(b * S_) + blockrow + row) * D_ + h * HD_ + tc4];
    qt[row][tc4 + 0] = __float2half(featmap(qv.x));
    qt[row][tc4 + 1] = __float2half(featmap(qv.y));
    qt[row][tc4 + 2] = __float2half(featmap(qv.z));
    qt[row][tc4 + 3] = __float2half(featmap(qv.w));
  }
  // ---- stage kv tile (f32 -> f16) + kred
  {
    __half* kvflat = &kvt[0][0];
#pragma unroll
    for (int i = 0; i < 8; ++i) {
      const int idx = i * 512 + t * 2;
      float2 kvv = *(const float2*)&kvg[(size_t)bh * 4096 + idx];
      kvflat[idx]     = __float2half(kvv.x);
      kvflat[idx + 1] = __float2half(kvv.y);
    }
    if (t < 16) {
      float4 kr = *(const float4*)&kredg[bh * 64 + t * 4];
      kreds[t * 4 + 0] = kr.x; kreds[t * 4 + 1] = kr.y;
      kreds[t * 4 + 2] = kr.z; kreds[t * 4 + 3] = kr.w;
    }
  }
  __syncthreads();

  float acc[8][8];
#pragma unroll
  for (int i = 0; i < 8; ++i)
#pragma unroll
    for (int j = 0; j < 8; ++j) acc[i][j] = 0.f;
  float zacc[8];
#pragma unroll
  for (int i = 0; i < 8; ++i) zacc[i] = 0.f;

#pragma unroll 1
  for (int kc = 0; kc < 16; ++kc) {
    // q packs: 8 rows (stride 8), 4 halves each (b64, conflict-free)
    __half2 qp[8][2];
#pragma unroll
    for (int rr = 0; rr < 8; ++rr) {
      float2 qraw = *(const float2*)&qt[lrow0 + 8 * rr][kc * 4];
      qp[rr][0] = asH2(qraw.x);
      qp[rr][1] = asH2(qraw.y);
    }
    float4 kr4 = *(const float4*)&kreds[kc * 4];
    const float krj[4] = {kr4.x, kr4.y, kr4.z, kr4.w};
#pragma unroll
    for (int j = 0; j < 4; ++j) {
      const int k = kc * 4 + j;
      float4 kvraw = *(const float4*)&kvt[k][cg * 8];   // 8 halves (b128)
      __half2 kvh[4] = {asH2(kvraw.x), asH2(kvraw.y), asH2(kvraw.z), asH2(kvraw.w)};
      float kvf[8];
#pragma unroll
      for (int p = 0; p < 4; ++p) {
        kvf[2 * p] = __low2float(kvh[p]);
        kvf[2 * p + 1] = __high2float(kvh[p]);
      }
#pragma unroll
      for (int rr = 0; rr < 8; ++rr) {
        const float qf = (j == 0) ? __low2float(qp[rr][0])
                       : (j == 1) ? __high2float(qp[rr][0])
                       : (j == 2) ? __low2float(qp[rr][1])
                                  : __high2float(qp[rr][1]);
        zacc[rr] += qf * krj[j];
#pragma unroll
        for (int e = 0; e < 8; ++e) acc[rr][e] += qf * kvf[e];
      }
    }
  }

  // ---- epilogue: scale by z, write out
#pragma unroll
  for (int rr = 0; rr < 8; ++rr) {
    const float z = __builtin_amdgcn_rcpf(zacc[rr]);
    const int grow = blockrow + w * 64 + rg + 8 * rr;
    float* op = &outg[((size_t)(b * S_) + grow) * D_ + h * HD_ + cg * 8];
    float4 o0 = {acc[rr][0] * z, acc[rr][1] * z, acc[rr][2] * z, acc[rr][3] * z};
    float4 o1 = {acc[rr][4] * z, acc[rr][5] * z, acc[rr][6] * z, acc[rr][7] * z};
    *(float4*)op = o0;
    *(float4*)(op + 4) = o1;
  }
}

extern "C" void kernel_launch(void* const* d_in, const int* in_sizes, int n_in,
                              void* d_out, int out_size, void* d_ws, size_t ws_size,
                              hipStream_t stream) {
  const float* q = (const float*)d_in[0];
  const float* k = (const float*)d_in[1];
  const float* v = (const float*)d_in[2];
  float* out = (float*)d_out;
  float* ws = (float*)d_ws;

  float* kv   = ws;                    // 1 MiB
  float* kred = ws + 262144;           // 16 KiB
  float* kvp  = ws + 262144 + 4096;    // NC MiB

  // nc=16 needs ~17.3 MB of ws; fall back to proven nc=8 (~9.4 MB, R1 ran it)
  if (ws_size >= (size_t)18 * 1024 * 1024) {
    constexpr int NC = 16;
    float* kredp = kvp + (size_t)NC * 262144;
    mh_p1<NC> <<<64 * NC, 256, 0, stream>>>(k, v, kvp, kredp);
    mh_p15<NC><<<1024,    256, 0, stream>>>(kvp, kredp, kv, kred);
  } else {
    constexpr int NC = 8;
    float* kredp = kvp + (size_t)NC * 262144;
    mh_p1<NC> <<<64 * NC, 256, 0, stream>>>(k, v, kvp, kredp);
    mh_p15<NC><<<1024,    256, 0, stream>>>(kvp, kredp, kv, kred);
  }
  mh_p2<<<64 * 16, 256, 0, stream>>>(q, kv, kred, out);
}

// Round 9
// 89.939 us; speedup vs baseline: 12.1603x; 1.0451x over previous
//
#include <hip/hip_runtime.h>
#include <hip/hip_fp16.h>

#define B_ 4
#define S_ 4096
#define H_ 16
#define D_ 1024
#define HD_ 64
#define NC_ 16   // 1024 blocks; ws proven >= 18MB in R5 (WRITE_SIZE showed NC=16 ran)

typedef _Float16 h2 __attribute__((ext_vector_type(2)));
union FH2 { float f; h2 h; };
__device__ __forceinline__ h2 asHH(float f) { FH2 u; u.f = f; return u.h; }

// pack two f32 -> half2 (round toward zero); bit-cast fixes clang's
// __fp16-vector vs _Float16-vector type mismatch (same 32 bits).
__device__ __forceinline__ h2 pkrtz(float a, float b) {
  auto r = __builtin_amdgcn_cvt_pkrtz(a, b);
  h2 out;
  __builtin_memcpy(&out, &r, 4);
  return out;
}

// (tanh(x)+1)/2 == sigmoid(2x)
__device__ __forceinline__ float featmap(float x) {
  float e = __expf(-2.0f * x);
  return __builtin_amdgcn_rcpf(1.0f + e);
}

__device__ __forceinline__ float dot2acc(h2 a, h2 b, float c) {
#if __has_builtin(__builtin_amdgcn_fdot2)
  return __builtin_amdgcn_fdot2(a, b, c, false);
#else
  return c + (float)a[0] * (float)b[0] + (float)a[1] * (float)b[1];
#endif
}

union F2H2 { float f; __half2 h; };
__device__ __forceinline__ __half2 asH2(float f) { F2H2 u; u.f = f; return u.h; }

// ---------------- Phase 1: partial KV (64x64) + partial ksum per (b,h,chunk)
// Row-PAIR f16 packing: kp[pair][d] = (kh[2p][d], kh[2p+1][d]) as half2.
// Per pair per lane: 4 ds_read_b128 + 64 v_dot2_f32_f16 (halves both LDS
// instruction count and VALU vs f32-FMA). f32 accumulate (precision kept).
__global__ __launch_bounds__(256, 2) void mh_p1(
    const float* __restrict__ kg, const float* __restrict__ vg,
    float* __restrict__ kvp, float* __restrict__ kredp) {
  __shared__ __align__(16) char pool[16384];
  h2 (*kp)[64] = (h2(*)[64])pool;            // 8KB: 32 pairs x 64 d
  h2 (*vp)[64] = (h2(*)[64])(pool + 8192);   // 8KB
  float* sA = (float*)pool;                  // 16KB overlay (reduction phase)
  __shared__ float ksr[4][64];

  const int bid = blockIdx.x;       // 0..64*NC_-1
  const int bh  = bid & 63;         // b*16+h
  const int c   = bid >> 6;         // chunk
  const int b   = bh >> 4, h = bh & 15;
  const int t    = threadIdx.x;
  const int w    = t >> 6;          // wave 0..3
  const int lane = t & 63;
  const int dg = lane >> 3, eg = lane & 7;
  const int d0 = dg * 8, e0 = eg * 8;

  const size_t rowbase = (size_t)b * S_ * D_ + (size_t)h * HD_;
  const float* kb = kg + rowbase;
  const float* vb = vg + rowbase;
  constexpr int CH = S_ / NC_;      // 256 rows per block
  const int s0 = c * CH;

  float acc[8][8];
#pragma unroll
  for (int i = 0; i < 8; ++i)
#pragma unroll
    for (int j = 0; j < 8; ++j) acc[i][j] = 0.f;
  float ks = 0.f;  // partial column-sum of sigmoid(k), column = lane

#pragma unroll 1
  for (int tile = 0; tile < CH / 64; ++tile) {
    const int rb = s0 + tile * 64 + w * 16;
    // wave w owns pairs [w*8, w*8+8) -> no cross-wave hazard, no barrier
#pragma unroll
    for (int p = 0; p < 8; ++p) {
      const int r0 = rb + 2 * p;
      float k0 = kb[(size_t)r0 * D_ + lane];
      float k1 = kb[(size_t)(r0 + 1) * D_ + lane];
      float v0 = vb[(size_t)r0 * D_ + lane];
      float v1 = vb[(size_t)(r0 + 1) * D_ + lane];
      float kh0 = featmap(k0), kh1 = featmap(k1);
      ks += kh0 + kh1;
      kp[w * 8 + p][lane] = pkrtz(kh0, kh1);
      vp[w * 8 + p][lane] = pkrtz(v0, v1);
    }
#pragma unroll
    for (int p = 0; p < 8; ++p) {
      const int pp = w * 8 + p;
      float4 kr0 = *(const float4*)&kp[pp][d0];       // 4 h2 (d0..d0+3)
      float4 kr1 = *(const float4*)&kp[pp][d0 + 4];   // 4 h2 (d0+4..d0+7)
      float4 vr0 = *(const float4*)&vp[pp][e0];
      float4 vr1 = *(const float4*)&vp[pp][e0 + 4];
      h2 kd[8] = {asHH(kr0.x), asHH(kr0.y), asHH(kr0.z), asHH(kr0.w),
                  asHH(kr1.x), asHH(kr1.y), asHH(kr1.z), asHH(kr1.w)};
      h2 ve[8] = {asHH(vr0.x), asHH(vr0.y), asHH(vr0.z), asHH(vr0.w),
                  asHH(vr1.x), asHH(vr1.y), asHH(vr1.z), asHH(vr1.w)};
#pragma unroll
      for (int di = 0; di < 8; ++di)
#pragma unroll
        for (int ej = 0; ej < 8; ++ej)
          acc[di][ej] = dot2acc(kd[di], ve[ej], acc[di][ej]);
    }
  }

  // ---- reduce 4 wave replicas sequentially through 16KB overlay, no atomics
  ksr[w][lane] = ks;
  __syncthreads();   // everyone done with kp/vp -> safe to overlay sA

#define STORE_ACC(dst)                                              \
  _Pragma("unroll") for (int di = 0; di < 8; ++di) {                \
    float4 a = {acc[di][0], acc[di][1], acc[di][2], acc[di][3]};    \
    float4 bq = {acc[di][4], acc[di][5], acc[di][6], acc[di][7]};   \
    *(float4*)&(dst)[(d0 + di) * 64 + e0] = a;                      \
    *(float4*)&(dst)[(d0 + di) * 64 + e0 + 4] = bq;                 \
  }
#define ADD_ACC(src)                                                \
  _Pragma("unroll") for (int di = 0; di < 8; ++di)                  \
    _Pragma("unroll") for (int ej = 0; ej < 8; ++ej)                \
      acc[di][ej] += (src)[(d0 + di) * 64 + e0 + ej];

  if (w == 3) STORE_ACC(sA);
  __syncthreads();
  if (w == 1) ADD_ACC(sA);
  __syncthreads();
  if (w == 2) STORE_ACC(sA);
  __syncthreads();
  if (w == 0) ADD_ACC(sA);
  __syncthreads();
  if (w == 1) STORE_ACC(sA);
  __syncthreads();
  if (w == 0) {
    ADD_ACC(sA);
    float* dst = kvp + ((size_t)(c * 64 + bh)) * 4096;
    STORE_ACC(dst);
  }
  if (t < 64) {
    float tot = ksr[0][t] + ksr[1][t] + ksr[2][t] + ksr[3][t];
    kredp[(size_t)(c * 64 + bh) * 64 + t] = tot;
  }
#undef STORE_ACC
#undef ADD_ACC
}

// ---------------- Phase 1.5: reduce chunk partials -> kv, kred
__global__ __launch_bounds__(256) void mh_p15(
    const float* __restrict__ kvp, const float* __restrict__ kredp,
    float* __restrict__ kv, float* __restrict__ kred) {
  const int i = blockIdx.x * 256 + threadIdx.x;  // 0..262143
  float s = 0.f;
#pragma unroll
  for (int c = 0; c < NC_; ++c) s += kvp[(size_t)c * (64 * 4096) + i];
  kv[i] = s;
  if (i < 64 * 64) {
    float r = 0.f;
#pragma unroll
    for (int c = 0; c < NC_; ++c) r += kredp[c * 4096 + i];
    kred[i] = r + 1e-8f;
  }
}

// ---------------- Phase 2: out = z * qh @ KV  (register-tiled via LDS)
// Proven ~20us in R5 -- kept verbatim.
__global__ __launch_bounds__(256, 3) void mh_p2(
    const float* __restrict__ qg, const float* __restrict__ kvg,
    const float* __restrict__ kredg, float* __restrict__ outg) {
  __shared__ __half qt[256][68];   // 34816 B
  __shared__ __half kvt[64][64];   // 8192 B
  __shared__ float kreds[64];

  const int bid = blockIdx.x;          // 0..1023
  const int bh = bid >> 4;             // 0..63
  const int chunk = bid & 15;
  const int b = bh >> 4, h = bh & 15;
  const int blockrow = chunk * 256;
  const int t = threadIdx.x;
  const int w = t >> 6, lane = t & 63;
  const int rg = lane >> 3, cg = lane & 7;
  const int lrow0 = w * 64 + rg;       // lane's rows: lrow0 + 8*rr

  // ---- stage q tile (featmap -> f16), coalesced
  const int tr = t >> 4, tc4 = (t & 15) * 4;
#pragma unroll
  for (int i = 0; i < 16; ++i) {
    const int row = tr + i * 16;
    float4 qv = *(const float4*)&qg[((size_t)(b * S_) + blockrow + row) * D_ + h * HD_ + tc4];
    qt[row][tc4 + 0] = __float2half(featmap(qv.x));
    qt[row][tc4 + 1] = __float2half(featmap(qv.y));
    qt[row][tc4 + 2] = __float2half(featmap(qv.z));
    qt[row][tc4 + 3] = __float2half(featmap(qv.w));
  }
  // ---- stage kv tile (f32 -> f16) + kred
  {
    __half* kvflat = &kvt[0][0];
#pragma unroll
    for (int i = 0; i < 8; ++i) {
      const int idx = i * 512 + t * 2;
      float2 kvv = *(const float2*)&kvg[(size_t)bh * 4096 + idx];
      kvflat[idx]     = __float2half(kvv.x);
      kvflat[idx + 1] = __float2half(kvv.y);
    }
    if (t < 16) {
      float4 kr = *(const float4*)&kredg[bh * 64 + t * 4];
      kreds[t * 4 + 0] = kr.x; kreds[t * 4 + 1] = kr.y;
      kreds[t * 4 + 2] = kr.z; kreds[t * 4 + 3] = kr.w;
    }
  }
  __syncthreads();

  float acc[8][8];
#pragma unroll
  for (int i = 0; i < 8; ++i)
#pragma unroll
    for (int j = 0; j < 8; ++j) acc[i][j] = 0.f;
  float zacc[8];
#pragma unroll
  for (int i = 0; i < 8; ++i) zacc[i] = 0.f;

#pragma unroll 1
  for (int kc = 0; kc < 16; ++kc) {
    // q packs: 8 rows (stride 8), 4 halves each (b64, conflict-free)
    __half2 qp[8][2];
#pragma unroll
    for (int rr = 0; rr < 8; ++rr) {
      float2 qraw = *(const float2*)&qt[lrow0 + 8 * rr][kc * 4];
      qp[rr][0] = asH2(qraw.x);
      qp[rr][1] = asH2(qraw.y);
    }
    float4 kr4 = *(const float4*)&kreds[kc * 4];
    const float krj[4] = {kr4.x, kr4.y, kr4.z, kr4.w};
#pragma unroll
    for (int j = 0; j < 4; ++j) {
      const int k = kc * 4 + j;
      float4 kvraw = *(const float4*)&kvt[k][cg * 8];   // 8 halves (b128)
      __half2 kvh[4] = {asH2(kvraw.x), asH2(kvraw.y), asH2(kvraw.z), asH2(kvraw.w)};
      float kvf[8];
#pragma unroll
      for (int p = 0; p < 4; ++p) {
        kvf[2 * p] = __low2float(kvh[p]);
        kvf[2 * p + 1] = __high2float(kvh[p]);
      }
#pragma unroll
      for (int rr = 0; rr < 8; ++rr) {
        const float qf = (j == 0) ? __low2float(qp[rr][0])
                       : (j == 1) ? __high2float(qp[rr][0])
                       : (j == 2) ? __low2float(qp[rr][1])
                                  : __high2float(qp[rr][1]);
        zacc[rr] += qf * krj[j];
#pragma unroll
        for (int e = 0; e < 8; ++e) acc[rr][e] += qf * kvf[e];
      }
    }
  }

  // ---- epilogue: scale by z, write out
#pragma unroll
  for (int rr = 0; rr < 8; ++rr) {
    const float z = __builtin_amdgcn_rcpf(zacc[rr]);
    const int grow = blockrow + w * 64 + rg + 8 * rr;
    float* op = &outg[((size_t)(b * S_) + grow) * D_ + h * HD_ + cg * 8];
    float4 o0 = {acc[rr][0] * z, acc[rr][1] * z, acc[rr][2] * z, acc[rr][3] * z};
    float4 o1 = {acc[rr][4] * z, acc[rr][5] * z, acc[rr][6] * z, acc[rr][7] * z};
    *(float4*)op = o0;
    *(float4*)(op + 4) = o1;
  }
}

extern "C" void kernel_launch(void* const* d_in, const int* in_sizes, int n_in,
                              void* d_out, int out_size, void* d_ws, size_t ws_size,
                              hipStream_t stream) {
  const float* q = (const float*)d_in[0];
  const float* k = (const float*)d_in[1];
  const float* v = (const float*)d_in[2];
  float* out = (float*)d_out;
  float* ws = (float*)d_ws;

  float* kv    = ws;                          // 1 MiB
  float* kred  = ws + 262144;                 // 16 KiB
  float* kvp   = ws + 262144 + 4096;          // NC_ MiB
  float* kredp = kvp + (size_t)NC_ * 262144;  // NC_*16 KiB

  mh_p1 <<<64 * NC_, 256, 0, stream>>>(k, v, kvp, kredp);
  mh_p15<<<1024,     256, 0, stream>>>(kvp, kredp, kv, kred);
  mh_p2 <<<64 * 16,  256, 0, stream>>>(q, kv, kred, out);
}

// Round 10
// 78.931 us; speedup vs baseline: 13.8562x; 1.1395x over previous
//
#include <hip/hip_runtime.h>
#include <hip/hip_fp16.h>

#define B_ 4
#define S_ 4096
#define H_ 16
#define D_ 1024
#define HD_ 64
#define NC_ 16   // 1024 blocks; ws >= 18MB proven in R5

typedef __fp16 hf8 __attribute__((ext_vector_type(8)));
typedef float f32x4 __attribute__((ext_vector_type(4)));

// (tanh(x)+1)/2 == sigmoid(2x)
__device__ __forceinline__ float featmap(float x) {
  float e = __expf(-2.0f * x);
  return __builtin_amdgcn_rcpf(1.0f + e);
}

union F2H2 { float f; __half2 h; };
__device__ __forceinline__ __half2 asH2(float f) { F2H2 u; u.f = f; return u.h; }

// ---------------- Phase 1 (MFMA): kvp[c,bh] = khT(64d x 256s) @ v(256s x 64e)
// LDS: khT [d=64][s=64] f16 and vT [e=64][s=64] f16, each row 128B with XOR
// swizzle byte ^= ((row&7)<<4)  -> ds_read_b128 of A/B frags is 8-deep
// bank-balanced (the floor), staging writes are 8-way (acceptable, ~3us).
// Each wave owns d-rows [w*16,w*16+16) x all e: accumulates 4 f32x4 frags
// across all 8 K-steps -> NO cross-wave reduction tree at all.
__global__ __launch_bounds__(256, 2) void mh_p1(
    const float* __restrict__ kg, const float* __restrict__ vg,
    float* __restrict__ kvp, float* __restrict__ kredp) {
  __shared__ __align__(16) char khT[8192];
  __shared__ __align__(16) char vT[8192];
  __shared__ float ksr[4][64];

  const int bid = blockIdx.x;       // 0..1023
  const int bh = bid & 63, c = bid >> 6;
  const int b = bh >> 4, h = bh & 15;
  const int t = threadIdx.x, w = t >> 6, l = t & 63;

  const size_t rowbase = (size_t)b * S_ * D_ + (size_t)h * HD_;
  const float* kb = kg + rowbase;
  const float* vb = vg + rowbase;
  const int s0 = c * 256;

  f32x4 acc[4];
#pragma unroll
  for (int et = 0; et < 4; ++et) acc[et] = (f32x4){0.f, 0.f, 0.f, 0.f};
  float ks = 0.f;                    // column-sum of featmap(k), column = l

  const int swz = (l & 7) << 4;      // staging swizzle (row of T-layout = l)
  const int arow = l & 15;           // frag row (d_local / e_local)
  const int kgrp = (l >> 4) * 8;     // frag k-offset in elements

#pragma unroll 1
  for (int tile = 0; tile < 4; ++tile) {
    const int rb = s0 + tile * 64 + w * 16;
    // stage: wave w -> s-slots [w*16, w*16+16) (8 row-pairs), lane l -> col l
#pragma unroll
    for (int p = 0; p < 8; ++p) {
      const int r0 = rb + 2 * p;
      float k0 = kb[(size_t)r0 * D_ + l];
      float k1 = kb[(size_t)(r0 + 1) * D_ + l];
      float v0 = vb[(size_t)r0 * D_ + l];
      float v1 = vb[(size_t)(r0 + 1) * D_ + l];
      float kh0 = featmap(k0), kh1 = featmap(k1);
      ks += kh0 + kh1;
      const int so = (w * 16 + 2 * p) * 2;   // byte offset of s-pair in row
      auto kpk = __builtin_amdgcn_cvt_pkrtz(kh0, kh1);
      auto vpk = __builtin_amdgcn_cvt_pkrtz(v0, v1);
      unsigned kb32, vb32;
      __builtin_memcpy(&kb32, &kpk, 4);
      __builtin_memcpy(&vb32, &vpk, 4);
      *(unsigned*)&khT[l * 128 + (so ^ swz)] = kb32;
      *(unsigned*)&vT [l * 128 + (so ^ swz)] = vb32;
    }
    __syncthreads();
    // compute: 2 K-steps of 32, 4 e-tiles; A reused across e-tiles
#pragma unroll
    for (int kk = 0; kk < 2; ++kk) {
      const int sbyte = (kk * 32 + kgrp) * 2;
      hf8 af;
      {
        const int d = w * 16 + arow;
        float4 tmp = *(const float4*)&khT[d * 128 + (sbyte ^ ((d & 7) << 4))];
        __builtin_memcpy(&af, &tmp, 16);
      }
#pragma unroll
      for (int et = 0; et < 4; ++et) {
        const int e = et * 16 + arow;
        hf8 bf;
        float4 tmp = *(const float4*)&vT[e * 128 + (sbyte ^ ((e & 7) << 4))];
        __builtin_memcpy(&bf, &tmp, 16);
        acc[et] = __builtin_amdgcn_mfma_f32_16x16x32_f16(af, bf, acc[et], 0, 0, 0);
      }
    }
    __syncthreads();
  }

  // ---- write: wave w owns d-rows [w*16, w*16+16); C/D: col=l&15, row=(l>>4)*4+r
  {
    float* dst = kvp + ((size_t)(c * 64 + bh)) * 4096;
    const int col = l & 15, rg4 = (l >> 4) * 4;
#pragma unroll
    for (int et = 0; et < 4; ++et)
#pragma unroll
      for (int r = 0; r < 4; ++r)
        dst[(w * 16 + rg4 + r) * 64 + et * 16 + col] = acc[et][r];
  }
  // ---- kred partials
  ksr[w][l] = ks;
  __syncthreads();
  if (t < 64) {
    kredp[(size_t)(c * 64 + bh) * 64 + t] =
        ksr[0][t] + ksr[1][t] + ksr[2][t] + ksr[3][t];
  }
}

// ---------------- Phase 1.5: reduce chunk partials -> kv, kred
__global__ __launch_bounds__(256) void mh_p15(
    const float* __restrict__ kvp, const float* __restrict__ kredp,
    float* __restrict__ kv, float* __restrict__ kred) {
  const int i = blockIdx.x * 256 + threadIdx.x;  // 0..262143
  float s = 0.f;
#pragma unroll
  for (int c = 0; c < NC_; ++c) s += kvp[(size_t)c * (64 * 4096) + i];
  kv[i] = s;
  if (i < 64 * 64) {
    float r = 0.f;
#pragma unroll
    for (int c = 0; c < NC_; ++c) r += kredp[c * 4096 + i];
    kred[i] = r + 1e-8f;
  }
}

// ---------------- Phase 2: out = z * qh @ KV  (register-tiled via LDS)
// Proven in R5/R9 -- kept verbatim.
__global__ __launch_bounds__(256, 3) void mh_p2(
    const float* __restrict__ qg, const float* __restrict__ kvg,
    const float* __restrict__ kredg, float* __restrict__ outg) {
  __shared__ __half qt[256][68];   // 34816 B
  __shared__ __half kvt[64][64];   // 8192 B
  __shared__ float kreds[64];

  const int bid = blockIdx.x;          // 0..1023
  const int bh = bid >> 4;             // 0..63
  const int chunk = bid & 15;
  const int b = bh >> 4, h = bh & 15;
  const int blockrow = chunk * 256;
  const int t = threadIdx.x;
  const int w = t >> 6, lane = t & 63;
  const int rg = lane >> 3, cg = lane & 7;
  const int lrow0 = w * 64 + rg;       // lane's rows: lrow0 + 8*rr

  // ---- stage q tile (featmap -> f16), coalesced
  const int tr = t >> 4, tc4 = (t & 15) * 4;
#pragma unroll
  for (int i = 0; i < 16; ++i) {
    const int row = tr + i * 16;
    float4 qv = *(const float4*)&qg[((size_t)(b * S_) + blockrow + row) * D_ + h * HD_ + tc4];
    qt[row][tc4 + 0] = __float2half(featmap(qv.x));
    qt[row][tc4 + 1] = __float2half(featmap(qv.y));
    qt[row][tc4 + 2] = __float2half(featmap(qv.z));
    qt[row][tc4 + 3] = __float2half(featmap(qv.w));
  }
  // ---- stage kv tile (f32 -> f16) + kred
  {
    __half* kvflat = &kvt[0][0];
#pragma unroll
    for (int i = 0; i < 8; ++i) {
      const int idx = i * 512 + t * 2;
      float2 kvv = *(const float2*)&kvg[(size_t)bh * 4096 + idx];
      kvflat[idx]     = __float2half(kvv.x);
      kvflat[idx + 1] = __float2half(kvv.y);
    }
    if (t < 16) {
      float4 kr = *(const float4*)&kredg[bh * 64 + t * 4];
      kreds[t * 4 + 0] = kr.x; kreds[t * 4 + 1] = kr.y;
      kreds[t * 4 + 2] = kr.z; kreds[t * 4 + 3] = kr.w;
    }
  }
  __syncthreads();

  float acc[8][8];
#pragma unroll
  for (int i = 0; i < 8; ++i)
#pragma unroll
    for (int j = 0; j < 8; ++j) acc[i][j] = 0.f;
  float zacc[8];
#pragma unroll
  for (int i = 0; i < 8; ++i) zacc[i] = 0.f;

#pragma unroll 1
  for (int kc = 0; kc < 16; ++kc) {
    // q packs: 8 rows (stride 8), 4 halves each (b64, conflict-free)
    __half2 qp[8][2];
#pragma unroll
    for (int rr = 0; rr < 8; ++rr) {
      float2 qraw = *(const float2*)&qt[lrow0 + 8 * rr][kc * 4];
      qp[rr][0] = asH2(qraw.x);
      qp[rr][1] = asH2(qraw.y);
    }
    float4 kr4 = *(const float4*)&kreds[kc * 4];
    const float krj[4] = {kr4.x, kr4.y, kr4.z, kr4.w};
#pragma unroll
    for (int j = 0; j < 4; ++j) {
      const int k = kc * 4 + j;
      float4 kvraw = *(const float4*)&kvt[k][cg * 8];   // 8 halves (b128)
      __half2 kvh[4] = {asH2(kvraw.x), asH2(kvraw.y), asH2(kvraw.z), asH2(kvraw.w)};
      float kvf[8];
#pragma unroll
      for (int p = 0; p < 4; ++p) {
        kvf[2 * p] = __low2float(kvh[p]);
        kvf[2 * p + 1] = __high2float(kvh[p]);
      }
#pragma unroll
      for (int rr = 0; rr < 8; ++rr) {
        const float qf = (j == 0) ? __low2float(qp[rr][0])
                       : (j == 1) ? __high2float(qp[rr][0])
                       : (j == 2) ? __low2float(qp[rr][1])
                                  : __high2float(qp[rr][1]);
        zacc[rr] += qf * krj[j];
#pragma unroll
        for (int e = 0; e < 8; ++e) acc[rr][e] += qf * kvf[e];
      }
    }
  }

  // ---- epilogue: scale by z, write out
#pragma unroll
  for (int rr = 0; rr < 8; ++rr) {
    const float z = __builtin_amdgcn_rcpf(zacc[rr]);
    const int grow = blockrow + w * 64 + rg + 8 * rr;
    float* op = &outg[((size_t)(b * S_) + grow) * D_ + h * HD_ + cg * 8];
    float4 o0 = {acc[rr][0] * z, acc[rr][1] * z, acc[rr][2] * z, acc[rr][3] * z};
    float4 o1 = {acc[rr][4] * z, acc[rr][5] * z, acc[rr][6] * z, acc[rr][7] * z};
    *(float4*)op = o0;
    *(float4*)(op + 4) = o1;
  }
}

extern "C" void kernel_launch(void* const* d_in, const int* in_sizes, int n_in,
                              void* d_out, int out_size, void* d_ws, size_t ws_size,
                              hipStream_t stream) {
  const float* q = (const float*)d_in[0];
  const float* k = (const float*)d_in[1];
  const float* v = (const float*)d_in[2];
  float* out = (float*)d_out;
  float* ws = (float*)d_ws;

  float* kv    = ws;                          // 1 MiB
  float* kred  = ws + 262144;                 // 16 KiB
  float* kvp   = ws + 262144 + 4096;          // NC_ MiB
  float* kredp = kvp + (size_t)NC_ * 262144;  // NC_*16 KiB

  mh_p1 <<<64 * NC_, 256, 0, stream>>>(k, v, kvp, kredp);
  mh_p15<<<1024,     256, 0, stream>>>(kvp, kredp, kv, kred);
  mh_p2 <<<64 * 16,  256, 0, stream>>>(q, kv, kred, out);
}

// Round 11
// 63.056 us; speedup vs baseline: 17.3445x; 1.2517x over previous
//
#include <hip/hip_runtime.h>
#include <hip/hip_fp16.h>

#define B_ 4
#define S_ 4096
#define H_ 16
#define D_ 1024
#define HD_ 64
#define NC_ 16   // 1024 blocks; ws >= 18MB proven in R5

typedef __fp16 hf8 __attribute__((ext_vector_type(8)));
typedef _Float16 h2 __attribute__((ext_vector_type(2)));
typedef float f32x4 __attribute__((ext_vector_type(4)));

// (tanh(x)+1)/2 == sigmoid(2x)
__device__ __forceinline__ float featmap(float x) {
  float e = __expf(-2.0f * x);
  return __builtin_amdgcn_rcpf(1.0f + e);
}

// pack two f32 -> 2xf16 in a u32 (round toward zero)
__device__ __forceinline__ unsigned pk2u(float a, float b) {
  auto r = __builtin_amdgcn_cvt_pkrtz(a, b);
  unsigned u;
  __builtin_memcpy(&u, &r, 4);
  return u;
}

__device__ __forceinline__ float dot2acc(h2 a, h2 b, float c) {
#if __has_builtin(__builtin_amdgcn_fdot2)
  return __builtin_amdgcn_fdot2(a, b, c, false);
#else
  return c + (float)a[0] * (float)b[0] + (float)a[1] * (float)b[1];
#endif
}

// ---------------- Phase 1 (MFMA): kvp[c,bh] = khT(64d x 256s) @ v(256s x 64e)
// Proven in R10 -- kept verbatim.
__global__ __launch_bounds__(256, 2) void mh_p1(
    const float* __restrict__ kg, const float* __restrict__ vg,
    float* __restrict__ kvp, float* __restrict__ kredp) {
  __shared__ __align__(16) char khT[8192];
  __shared__ __align__(16) char vT[8192];
  __shared__ float ksr[4][64];

  const int bid = blockIdx.x;       // 0..1023
  const int bh = bid & 63, c = bid >> 6;
  const int b = bh >> 4, h = bh & 15;
  const int t = threadIdx.x, w = t >> 6, l = t & 63;

  const size_t rowbase = (size_t)b * S_ * D_ + (size_t)h * HD_;
  const float* kb = kg + rowbase;
  const float* vb = vg + rowbase;
  const int s0 = c * 256;

  f32x4 acc[4];
#pragma unroll
  for (int et = 0; et < 4; ++et) acc[et] = (f32x4){0.f, 0.f, 0.f, 0.f};
  float ks = 0.f;                    // column-sum of featmap(k), column = l

  const int swz = (l & 7) << 4;      // staging swizzle (row of T-layout = l)
  const int arow = l & 15;           // frag row (d_local / e_local)
  const int kgrp = (l >> 4) * 8;     // frag k-offset in elements

#pragma unroll 1
  for (int tile = 0; tile < 4; ++tile) {
    const int rb = s0 + tile * 64 + w * 16;
#pragma unroll
    for (int p = 0; p < 8; ++p) {
      const int r0 = rb + 2 * p;
      float k0 = kb[(size_t)r0 * D_ + l];
      float k1 = kb[(size_t)(r0 + 1) * D_ + l];
      float v0 = vb[(size_t)r0 * D_ + l];
      float v1 = vb[(size_t)(r0 + 1) * D_ + l];
      float kh0 = featmap(k0), kh1 = featmap(k1);
      ks += kh0 + kh1;
      const int so = (w * 16 + 2 * p) * 2;   // byte offset of s-pair in row
      *(unsigned*)&khT[l * 128 + (so ^ swz)] = pk2u(kh0, kh1);
      *(unsigned*)&vT [l * 128 + (so ^ swz)] = pk2u(v0, v1);
    }
    __syncthreads();
#pragma unroll
    for (int kk = 0; kk < 2; ++kk) {
      const int sbyte = (kk * 32 + kgrp) * 2;
      hf8 af;
      {
        const int d = w * 16 + arow;
        float4 tmp = *(const float4*)&khT[d * 128 + (sbyte ^ ((d & 7) << 4))];
        __builtin_memcpy(&af, &tmp, 16);
      }
#pragma unroll
      for (int et = 0; et < 4; ++et) {
        const int e = et * 16 + arow;
        hf8 bf;
        float4 tmp = *(const float4*)&vT[e * 128 + (sbyte ^ ((e & 7) << 4))];
        __builtin_memcpy(&bf, &tmp, 16);
        acc[et] = __builtin_amdgcn_mfma_f32_16x16x32_f16(af, bf, acc[et], 0, 0, 0);
      }
    }
    __syncthreads();
  }

  {
    float* dst = kvp + ((size_t)(c * 64 + bh)) * 4096;
    const int col = l & 15, rg4 = (l >> 4) * 4;
#pragma unroll
    for (int et = 0; et < 4; ++et)
#pragma unroll
      for (int r = 0; r < 4; ++r)
        dst[(w * 16 + rg4 + r) * 64 + et * 16 + col] = acc[et][r];
  }
  ksr[w][l] = ks;
  __syncthreads();
  if (t < 64) {
    kredp[(size_t)(c * 64 + bh) * 64 + t] =
        ksr[0][t] + ksr[1][t] + ksr[2][t] + ksr[3][t];
  }
}

// ---------------- Phase 1.5: reduce chunk partials -> kv, kred
__global__ __launch_bounds__(256) void mh_p15(
    const float* __restrict__ kvp, const float* __restrict__ kredp,
    float* __restrict__ kv, float* __restrict__ kred) {
  const int i = blockIdx.x * 256 + threadIdx.x;  // 0..262143
  float s = 0.f;
#pragma unroll
  for (int c = 0; c < NC_; ++c) s += kvp[(size_t)c * (64 * 4096) + i];
  kv[i] = s;
  if (i < 64 * 64) {
    float r = 0.f;
#pragma unroll
    for (int c = 0; c < NC_; ++c) r += kredp[c * 4096 + i];
    kred[i] = r + 1e-8f;
  }
}

// ---------------- Phase 2 (MFMA): out = z * qh(256x64) @ kv(64x64) per block
// Same verified fragment recipe as P1: A = qt[row][k] f16 swizzled, B =
// kvT[e][k] f16 swizzled, C/D col=l&15 row=(l>>4)*4+reg. z = 1/(qh.kred)
// computed from A-frags via fdot2 + shfl_xor(16,32), redistributed to C/D
// rows with one shfl per reg. Wave w owns s-rows [w*64, w*64+64).
__global__ __launch_bounds__(256, 3) void mh_p2(
    const float* __restrict__ qg, const float* __restrict__ kvg,
    const float* __restrict__ kredg, float* __restrict__ outg) {
  __shared__ __align__(16) char qt[32768];   // 256 rows x 128B f16, swizzled
  __shared__ __align__(16) char kvT[8192];   // 64 e-rows x 128B f16, swizzled
  __shared__ __align__(16) char kredh[128];  // 64 f16

  const int bid = blockIdx.x;          // 0..1023
  const int bh = bid >> 4, chunk = bid & 15;
  const int b = bh >> 4, h = bh & 15;
  const int blockrow = chunk * 256;
  const int t = threadIdx.x, w = t >> 6, l = t & 63;

  // ---- stage q tile: featmap -> f16, swizzled rows (coalesced float4 reads)
  const int tr = t >> 4, tc = (t & 15) * 4;     // row base, f32 column
  const int swst = (tr & 7) << 4;               // row&7 == tr&7 (rows step by 16)
#pragma unroll
  for (int i = 0; i < 16; ++i) {
    const int row = tr + i * 16;
    float4 qv = *(const float4*)&qg[((size_t)(b * S_) + blockrow + row) * D_ + h * HD_ + tc];
    uint2 u = {pk2u(featmap(qv.x), featmap(qv.y)),
               pk2u(featmap(qv.z), featmap(qv.w))};
    *(uint2*)&qt[row * 128 + ((tc * 2) ^ swst)] = u;
  }
  // ---- stage kvT (transpose: [k][e] -> [e][k] f16, swizzled) + kred f16
#pragma unroll
  for (int i = 0; i < 16; ++i) {
    const int idx = i * 256 + t;
    const int kk = idx >> 6, e = idx & 63;
    *(__half*)&kvT[e * 128 + ((kk * 2) ^ ((e & 7) << 4))] =
        __float2half(kvg[(size_t)bh * 4096 + idx]);
  }
  if (t < 16) {
    float4 kr = *(const float4*)&kredg[bh * 64 + t * 4];
    uint2 u = {pk2u(kr.x, kr.y), pk2u(kr.z, kr.w)};
    *(uint2*)&kredh[t * 8] = u;
  }
  __syncthreads();

  const int col = l & 15;
  const int kB = (l >> 4) * 16;     // k-slice byte offset (8 f16)
  const int sw = (l & 7) << 4;

  f32x4 acc[4][4];
#pragma unroll
  for (int i = 0; i < 4; ++i)
#pragma unroll
    for (int j = 0; j < 4; ++j) acc[i][j] = (f32x4){0.f, 0.f, 0.f, 0.f};
  float zf[4];

  // kred k-slices (uniform per 16-lane group -> LDS broadcast)
  h2 kk0[4], kk1[4];
  {
    float4 r0 = *(const float4*)&kredh[kB];
    float4 r1 = *(const float4*)&kredh[64 + kB];
    __builtin_memcpy(kk0, &r0, 16);
    __builtin_memcpy(kk1, &r1, 16);
  }

#pragma unroll
  for (int rt = 0; rt < 4; ++rt) {
    const int row = w * 64 + rt * 16 + col;
    float4 a0r = *(const float4*)&qt[row * 128 + (kB ^ sw)];
    float4 a1r = *(const float4*)&qt[row * 128 + ((64 + kB) ^ sw)];
    hf8 af0, af1;
    __builtin_memcpy(&af0, &a0r, 16);
    __builtin_memcpy(&af1, &a1r, 16);
    // z partial: this lane's 16 k-elements dotted with kred
    h2 aa0[4], aa1[4];
    __builtin_memcpy(aa0, &a0r, 16);
    __builtin_memcpy(aa1, &a1r, 16);
    float zp = 0.f;
#pragma unroll
    for (int j = 0; j < 4; ++j) {
      zp = dot2acc(aa0[j], kk0[j], zp);
      zp = dot2acc(aa1[j], kk1[j], zp);
    }
    zp += __shfl_xor(zp, 16);
    zp += __shfl_xor(zp, 32);     // now every lane holds zacc for row (l&15)
    zf[rt] = __builtin_amdgcn_rcpf(zp);
#pragma unroll
    for (int et = 0; et < 4; ++et) {
      const int er = et * 16 + col;
      float4 b0r = *(const float4*)&kvT[er * 128 + (kB ^ sw)];
      float4 b1r = *(const float4*)&kvT[er * 128 + ((64 + kB) ^ sw)];
      hf8 bf0, bf1;
      __builtin_memcpy(&bf0, &b0r, 16);
      __builtin_memcpy(&bf1, &b1r, 16);
      acc[rt][et] = __builtin_amdgcn_mfma_f32_16x16x32_f16(af0, bf0, acc[rt][et], 0, 0, 0);
      acc[rt][et] = __builtin_amdgcn_mfma_f32_16x16x32_f16(af1, bf1, acc[rt][et], 0, 0, 0);
    }
  }

  // ---- epilogue: z-scale + write (C/D: col=l&15, row=(l>>4)*4+r)
  const int rg4 = (l >> 4) * 4;
#pragma unroll
  for (int rt = 0; rt < 4; ++rt) {
#pragma unroll
    for (int r = 0; r < 4; ++r) {
      const float zr = __shfl(zf[rt], rg4 + r);   // lane rg4+r holds z of that row
      const int grow = blockrow + w * 64 + rt * 16 + rg4 + r;
      float* op = &outg[((size_t)(b * S_) + grow) * D_ + h * HD_];
#pragma unroll
      for (int et = 0; et < 4; ++et)
        op[et * 16 + col] = acc[rt][et][r] * zr;
    }
  }
}

extern "C" void kernel_launch(void* const* d_in, const int* in_sizes, int n_in,
                              void* d_out, int out_size, void* d_ws, size_t ws_size,
                              hipStream_t stream) {
  const float* q = (const float*)d_in[0];
  const float* k = (const float*)d_in[1];
  const float* v = (const float*)d_in[2];
  float* out = (float*)d_out;
  float* ws = (float*)d_ws;

  float* kv    = ws;                          // 1 MiB
  float* kred  = ws + 262144;                 // 16 KiB
  float* kvp   = ws + 262144 + 4096;          // NC_ MiB
  float* kredp = kvp + (size_t)NC_ * 262144;  // NC_*16 KiB

  mh_p1 <<<64 * NC_, 256, 0, stream>>>(k, v, kvp, kredp);
  mh_p15<<<1024,     256, 0, stream>>>(kvp, kredp, kv, kred);
  mh_p2 <<<64 * 16,  256, 0, stream>>>(q, kv, kred, out);
}